// Round 5
// baseline (1293.645 us; speedup 1.0000x reference)
//
#include <hip/hip_runtime.h>
#include <hip/hip_bf16.h>

// B=512, S=64, IN=128, DM=256, H=8, HD=32, L=2, FF=1024, DO=64, E=8, K=2, GI=8192

typedef __attribute__((ext_vector_type(8))) short bf16x8;
typedef __attribute__((ext_vector_type(4))) float f32x4;
typedef __attribute__((ext_vector_type(4))) unsigned short u16x4;

#define DEVINL __device__ __forceinline__
#define MFMA16(a, b, c) __builtin_amdgcn_mfma_f32_16x16x32_bf16((a), (b), (c), 0, 0, 0)

DEVINL float b2f(unsigned short u) {
    unsigned int i = ((unsigned int)u) << 16;
    float f; __builtin_memcpy(&f, &i, 4); return f;
}
DEVINL unsigned short f2b(float f) {
    unsigned int i; __builtin_memcpy(&i, &f, 4);
    unsigned int r = (i + 0x7FFFu + ((i >> 16) & 1u)) >> 16;  // RTN-even
    return (unsigned short)r;
}

// ---------------------------------------------------------------------------
// prep: all weight transposes fp32 [R][C] -> bf16 [C][R] in ONE kernel,
// plus routing-counter zeroing (fewer launches; R4 lost ~400us outside expert)
__global__ __launch_bounds__(256) void prep_kernel(
    const float* __restrict__ Win, const float* __restrict__ Wq,
    const float* __restrict__ Wk,  const float* __restrict__ Wv,
    const float* __restrict__ Wo,  const float* __restrict__ W1,
    const float* __restrict__ W2,
    short* __restrict__ WinT, short* __restrict__ WqT, short* __restrict__ WkT,
    short* __restrict__ WvT,  short* __restrict__ WoT, short* __restrict__ W1T,
    short* __restrict__ W2T,  int* __restrict__ cnt)
{
    if (blockIdx.x == 0 && threadIdx.x < 8) cnt[threadIdx.x] = 0;
    int i = blockIdx.x * 256 + threadIdx.x;
    const float* src; short* dst; int lR, lC;
    if (i < 262144)                        { src = Win; dst = WinT; lR = 7;  lC = 8;  }
    else if ((i -= 262144)  < 1048576)     { src = Wq;  dst = WqT;  lR = 8;  lC = 8;  }
    else if ((i -= 1048576) < 1048576)     { src = Wk;  dst = WkT;  lR = 8;  lC = 8;  }
    else if ((i -= 1048576) < 1048576)     { src = Wv;  dst = WvT;  lR = 8;  lC = 8;  }
    else if ((i -= 1048576) < 1048576)     { src = Wo;  dst = WoT;  lR = 8;  lC = 8;  }
    else if ((i -= 1048576) < 4194304)     { src = W1;  dst = W1T;  lR = 8;  lC = 10; }
    else { i -= 4194304;                     src = W2;  dst = W2T;  lR = 10; lC = 8;  }
    int rc  = 1 << (lR + lC);
    int mat = i >> (lR + lC);
    int rem = i & (rc - 1);
    int c   = rem >> lR;
    int r   = rem & ((1 << lR) - 1);
    dst[i] = (short)f2b(src[((size_t)mat << (lR + lC)) + ((size_t)r << lC) + c]);
}

// ---------------------------------------------------------------------------
// gate: double-precision logits (stable top-2 vs numpy ref)
__global__ __launch_bounds__(256) void gate_kernel(
    const float* __restrict__ x, const float* __restrict__ Wg, const float* __restrict__ bg,
    int* __restrict__ cnt, int* __restrict__ rlist, float* __restrict__ wlist)
{
    const int b = blockIdx.x;
    const int tid = threadIdx.x;
    const int e8 = tid & 7;
    const int seg = tid >> 3;
    const float* gi = x + (size_t)b * 8192;
    double p = 0.0;
    for (int ii = 0; ii < 256; ++ii) {
        int i = seg * 256 + ii;
        p += (double)gi[i] * (double)Wg[i * 8 + e8];
    }
    p += __shfl_xor(p, 8, 64);
    p += __shfl_xor(p, 16, 64);
    p += __shfl_xor(p, 32, 64);
    __shared__ double wred[4 * 8];
    const int lane = tid & 63, w = tid >> 6;
    if (lane < 8) wred[w * 8 + lane] = p;
    __syncthreads();
    if (tid == 0) {
        double lg[8];
        for (int e = 0; e < 8; ++e)
            lg[e] = wred[e] + wred[8 + e] + wred[16 + e] + wred[24 + e] + (double)bg[e];
        int i1 = 0;
        for (int e = 1; e < 8; ++e) if (lg[e] > lg[i1]) i1 = e;
        int i2 = (i1 == 0) ? 1 : 0;
        for (int e = 0; e < 8; ++e) if (e != i1 && lg[e] > lg[i2]) i2 = e;
        double ex = exp(lg[i2] - lg[i1]);
        float w1 = (float)(1.0 / (1.0 + ex));
        float w2 = (float)(ex / (1.0 + ex));
        int p1 = atomicAdd(&cnt[i1], 1);
        rlist[i1 * 512 + p1] = b; wlist[i1 * 512 + p1] = w1;
        int p2 = atomicAdd(&cnt[i2], 1);
        rlist[i2 * 512 + p2] = b; wlist[i2 * 512 + p2] = w2;
    }
}

// ---------------------------------------------------------------------------
// resproj: 8 batch rows per block -> Wr stream reused 8x
__global__ __launch_bounds__(256) void resproj_kernel(
    const float* __restrict__ x, const float* __restrict__ Wr, const float* __restrict__ br,
    float* __restrict__ acc_out)
{
    const int b0 = blockIdx.x * 8;
    const int tid = threadIdx.x;
    const int d = tid & 63;
    const int part = tid >> 6;
    float acc[8];
    #pragma unroll
    for (int k = 0; k < 8; ++k) acc[k] = 0.f;
    for (int ii = 0; ii < 2048; ++ii) {
        int i = part * 2048 + ii;
        float wv = Wr[i * 64 + d];
        #pragma unroll
        for (int k = 0; k < 8; ++k) acc[k] += x[(size_t)(b0 + k) * 8192 + i] * wv;
    }
    __shared__ float rr[4][8][64];
    #pragma unroll
    for (int k = 0; k < 8; ++k) rr[part][k][d] = acc[k];
    __syncthreads();
    if (tid < 64) {
        #pragma unroll
        for (int k = 0; k < 8; ++k) {
            float v = rr[0][k][tid] + rr[1][k][tid] + rr[2][k][tid] + rr[3][k][tid];
            acc_out[(b0 + k) * 64 + tid] = 0.1f * (v + br[tid]);
        }
    }
}

// ---------------------------------------------------------------------------
// expert kernel — 512 threads / 8 waves, N-partitioned: wave w owns output
// cols [w*32, w*32+32) of every GEMM = exactly head w for attention (fully
// wave-private). 2 waves/SIMD so one wave's MFMAs hide the other's L2 loads.
// B-frags: wave-private global_load_dwordx4 from pre-transposed bf16 images
// (L2-resident per XCD via e=blockIdx&7 pin). A-frags: shared bf16 LDS (hS).
__global__ __launch_bounds__(512, 2) void expert_kernel(
    const float* __restrict__ x,
    const short* __restrict__ WinT, const float* __restrict__ bin_,
    const short* __restrict__ WqT,  const float* __restrict__ bq,
    const short* __restrict__ WkT,  const float* __restrict__ bk,
    const short* __restrict__ WvT,  const float* __restrict__ bv,
    const short* __restrict__ WoT,  const float* __restrict__ bo,
    const float* __restrict__ ln1g, const float* __restrict__ ln1b,
    const float* __restrict__ ln2g, const float* __restrict__ ln2b,
    const short* __restrict__ W1T,  const float* __restrict__ b1,
    const short* __restrict__ W2T,  const float* __restrict__ b2,
    const float* __restrict__ Wout, const float* __restrict__ bout,
    const int* __restrict__ cnt, const int* __restrict__ rlist,
    const float* __restrict__ wlist, float* __restrict__ acc_out)
{
    const int e = blockIdx.x & 7;          // XCD pin
    const int s = blockIdx.x >> 3;
    if (s >= cnt[e]) return;
    const int b   = rlist[e * 512 + s];
    const float wgt = wlist[e * 512 + s];
    const int tid = threadIdx.x;
    const int lane = tid & 63;
    const int w   = __builtin_amdgcn_readfirstlane(tid >> 6);  // 0..7
    const int ln = lane & 15, quad = lane >> 4;
    const int nb = w * 32;                 // wave's output-column base (= head w)

    // LDS: 33,792 + 118,784 + 4,096 = 156,672 B -> 1 block/CU, 8 waves
    __shared__ unsigned short hS[64 * 264];                   // residual (A-source)
    __shared__ __align__(16) unsigned short attnS[8 * 7424];  // per-wave attn | xS | tS
    __shared__ float redS[64 * 16];                           // LN partials / pooled
    unsigned short* Qw  = attnS + w * 7424;   // [64][40]
    unsigned short* Kw  = Qw + 2560;          // [64][40]
    unsigned short* VTw = Qw + 5120;          // [32][72]
    unsigned short* PSw = Qw;                 // [64][72] overlays Q+K
    unsigned short* xS  = attnS;              // [64][136] (block-shared, stage)
    unsigned short* tS  = attnS;              // [64][264] (block-shared, FF)
    float* pooledS = redS;                    // [256] (after LN2's barrier)

    // ---- stage x[b] -> xS bf16 row-major ----
    {
        const float* xb = x + (size_t)b * 8192;
        #pragma unroll
        for (int i = 0; i < 16; ++i) {
            int id = tid + 512 * i;
            xS[(id >> 7) * 136 + (id & 127)] = f2b(xb[id]);
        }
    }
    __syncthreads();

    f32x4 hr[8];   // residual, wave's 32 cols x 64 rows, C-layout [rt*2+ct2]

    // ---- P1: h0 = x @ Win + bin (K=128) ----
    {
        const short* BW = WinT + (size_t)e * 32768;
        const float* bp = bin_ + e * 256;
        bf16x8 Bf[8];
        #pragma unroll
        for (int ct2 = 0; ct2 < 2; ++ct2)
            #pragma unroll
            for (int kt = 0; kt < 4; ++kt)
                Bf[ct2 * 4 + kt] = *(const bf16x8*)(BW + (size_t)(nb + ct2 * 16 + ln) * 128 + kt * 32 + quad * 8);
        float bz[2];
        #pragma unroll
        for (int ct2 = 0; ct2 < 2; ++ct2) bz[ct2] = bp[nb + ct2 * 16 + ln];
        #pragma unroll
        for (int rt = 0; rt < 4; ++rt) {
            bf16x8 Af[4];
            #pragma unroll
            for (int kt = 0; kt < 4; ++kt)
                Af[kt] = *(const bf16x8*)&xS[(rt * 16 + ln) * 136 + kt * 32 + quad * 8];
            #pragma unroll
            for (int ct2 = 0; ct2 < 2; ++ct2) {
                f32x4 c = {bz[ct2], bz[ct2], bz[ct2], bz[ct2]};
                #pragma unroll
                for (int kt = 0; kt < 4; ++kt) c = MFMA16(Af[kt], Bf[ct2 * 4 + kt], c);
                hr[rt * 2 + ct2] = c;
                #pragma unroll
                for (int i = 0; i < 4; ++i)
                    hS[(rt * 16 + quad * 4 + i) * 264 + nb + ct2 * 16 + ln] = f2b(c[i]);
            }
        }
    }
    __syncthreads();

    // LayerNorm over acc (C-layout); 8-wave reduction via redS; writes hr + hS.
    auto LN = [&](f32x4* a, const float* g, const float* bb) {
        #pragma unroll
        for (int rt = 0; rt < 4; ++rt)
            #pragma unroll
            for (int i = 0; i < 4; ++i) {
                float s1 = a[rt * 2][i] + a[rt * 2 + 1][i];
                float s2 = a[rt * 2][i] * a[rt * 2][i] + a[rt * 2 + 1][i] * a[rt * 2 + 1][i];
                s1 += __shfl_xor(s1, 1); s1 += __shfl_xor(s1, 2);
                s1 += __shfl_xor(s1, 4); s1 += __shfl_xor(s1, 8);
                s2 += __shfl_xor(s2, 1); s2 += __shfl_xor(s2, 2);
                s2 += __shfl_xor(s2, 4); s2 += __shfl_xor(s2, 8);
                if (ln == 0) {
                    int row = rt * 16 + quad * 4 + i;
                    redS[row * 16 + w * 2]     = s1;
                    redS[row * 16 + w * 2 + 1] = s2;
                }
            }
        __syncthreads();
        float gv[2], bv2[2];
        #pragma unroll
        for (int ct2 = 0; ct2 < 2; ++ct2) { gv[ct2] = g[nb + ct2 * 16 + ln]; bv2[ct2] = bb[nb + ct2 * 16 + ln]; }
        #pragma unroll
        for (int rt = 0; rt < 4; ++rt)
            #pragma unroll
            for (int i = 0; i < 4; ++i) {
                int row = rt * 16 + quad * 4 + i;
                float S1 = 0.f, S2 = 0.f;
                #pragma unroll
                for (int ww = 0; ww < 8; ++ww) { S1 += redS[row * 16 + ww * 2]; S2 += redS[row * 16 + ww * 2 + 1]; }
                float m_ = S1 * (1.f / 256.f);
                float rstd = rsqrtf(S2 * (1.f / 256.f) - m_ * m_ + 1e-5f);
                #pragma unroll
                for (int ct2 = 0; ct2 < 2; ++ct2) {
                    float v = (a[rt * 2 + ct2][i] - m_) * rstd * gv[ct2] + bv2[ct2];
                    a[rt * 2 + ct2][i] = v;
                    hS[row * 264 + nb + ct2 * 16 + ln] = f2b(v);
                }
            }
        __syncthreads();
    };

    for (int l = 0; l < 2; ++l) {
        const int el = e * 2 + l;
        const short* WqE = WqT + (size_t)el * 65536;
        const short* WkE = WkT + (size_t)el * 65536;
        const short* WvE = WvT + (size_t)el * 65536;
        const short* WoE = WoT + (size_t)el * 65536;
        const short* W1E = W1T + (size_t)el * 262144;
        const short* W2E = W2T + (size_t)el * 262144;
        const float* bq_p = bq + el * 256;
        const float* bk_p = bk + el * 256;
        const float* bv_p = bv + el * 256;
        const float* bo_p = bo + el * 256;

        // ---- QKV for head w (N=32, K=256): outputs -> Qw/Kw row-major, V -> VTw ----
        #pragma unroll
        for (int m3 = 0; m3 < 3; ++m3) {
            const short* WB = (m3 == 0) ? WqE : (m3 == 1) ? WkE : WvE;
            const float* bm = (m3 == 0) ? bq_p : (m3 == 1) ? bk_p : bv_p;
            bf16x8 Bq[16];
            #pragma unroll
            for (int ct2 = 0; ct2 < 2; ++ct2)
                #pragma unroll
                for (int kt = 0; kt < 8; ++kt)
                    Bq[ct2 * 8 + kt] = *(const bf16x8*)(WB + (size_t)(nb + ct2 * 16 + ln) * 256 + kt * 32 + quad * 8);
            float bz2[2];
            #pragma unroll
            for (int ct2 = 0; ct2 < 2; ++ct2) bz2[ct2] = bm[nb + ct2 * 16 + ln];
            #pragma unroll
            for (int rt = 0; rt < 4; ++rt) {
                bf16x8 Af[8];
                #pragma unroll
                for (int kt = 0; kt < 8; ++kt)
                    Af[kt] = *(const bf16x8*)&hS[(rt * 16 + ln) * 264 + kt * 32 + quad * 8];
                #pragma unroll
                for (int ct2 = 0; ct2 < 2; ++ct2) {
                    f32x4 c = {bz2[ct2], bz2[ct2], bz2[ct2], bz2[ct2]};
                    #pragma unroll
                    for (int kt = 0; kt < 8; ++kt) c = MFMA16(Af[kt], Bq[ct2 * 8 + kt], c);
                    if (m3 == 0) {
                        #pragma unroll
                        for (int i = 0; i < 4; ++i)
                            Qw[(rt * 16 + quad * 4 + i) * 40 + ct2 * 16 + ln] = f2b(c[i]);
                    } else if (m3 == 1) {
                        #pragma unroll
                        for (int i = 0; i < 4; ++i)
                            Kw[(rt * 16 + quad * 4 + i) * 40 + ct2 * 16 + ln] = f2b(c[i]);
                    } else {
                        u16x4 pk;
                        #pragma unroll
                        for (int i = 0; i < 4; ++i) pk[i] = f2b(c[i]);
                        *(u16x4*)&VTw[(ct2 * 16 + ln) * 72 + rt * 16 + quad * 4] = pk;
                    }
                }
            }
        }

        // ---- S = Q K^T (M=64,N=64,K=32), wave-private ----
        f32x4 sc[16];
        {
            bf16x8 Bk[4];
            #pragma unroll
            for (int ck = 0; ck < 4; ++ck)
                Bk[ck] = *(const bf16x8*)&Kw[(ck * 16 + ln) * 40 + quad * 8];
            #pragma unroll
            for (int rt = 0; rt < 4; ++rt) {
                bf16x8 Aq = *(const bf16x8*)&Qw[(rt * 16 + ln) * 40 + quad * 8];
                #pragma unroll
                for (int ck = 0; ck < 4; ++ck) {
                    f32x4 z = {0.f, 0.f, 0.f, 0.f};
                    sc[rt * 4 + ck] = MFMA16(Aq, Bk[ck], z);
                }
            }
        }
        // ---- softmax per row (in-wave, 16-lane groups) -> PSw bf16 ----
        {
            const float sscale = 0.17677669529663687f;  // 1/sqrt(32)
            #pragma unroll
            for (int t = 0; t < 16; ++t)
                #pragma unroll
                for (int i = 0; i < 4; ++i) sc[t][i] *= sscale;
            #pragma unroll
            for (int rt = 0; rt < 4; ++rt)
                #pragma unroll
                for (int i = 0; i < 4; ++i) {
                    float m_ = fmaxf(fmaxf(sc[rt * 4 + 0][i], sc[rt * 4 + 1][i]),
                                     fmaxf(sc[rt * 4 + 2][i], sc[rt * 4 + 3][i]));
                    m_ = fmaxf(m_, __shfl_xor(m_, 1));
                    m_ = fmaxf(m_, __shfl_xor(m_, 2));
                    m_ = fmaxf(m_, __shfl_xor(m_, 4));
                    m_ = fmaxf(m_, __shfl_xor(m_, 8));
                    float s_ = 0.f;
                    #pragma unroll
                    for (int ck = 0; ck < 4; ++ck) {
                        sc[rt * 4 + ck][i] = __expf(sc[rt * 4 + ck][i] - m_);
                        s_ += sc[rt * 4 + ck][i];
                    }
                    s_ += __shfl_xor(s_, 1); s_ += __shfl_xor(s_, 2);
                    s_ += __shfl_xor(s_, 4); s_ += __shfl_xor(s_, 8);
                    float inv = 1.f / s_;
                    int row = rt * 16 + quad * 4 + i;
                    #pragma unroll
                    for (int ck = 0; ck < 4; ++ck)
                        PSw[row * 72 + ck * 16 + ln] = f2b(sc[rt * 4 + ck][i] * inv);
                }
        }

        // ---- av = P @ V (M=64,N=32,K=64), wave-private ----
        f32x4 avr[8];
        {
            bf16x8 Bv[4];
            #pragma unroll
            for (int ct2 = 0; ct2 < 2; ++ct2)
                #pragma unroll
                for (int kt2 = 0; kt2 < 2; ++kt2)
                    Bv[ct2 * 2 + kt2] = *(const bf16x8*)&VTw[(ct2 * 16 + ln) * 72 + kt2 * 32 + quad * 8];
            #pragma unroll
            for (int rt = 0; rt < 4; ++rt) {
                bf16x8 Ap[2];
                #pragma unroll
                for (int kt2 = 0; kt2 < 2; ++kt2)
                    Ap[kt2] = *(const bf16x8*)&PSw[(rt * 16 + ln) * 72 + kt2 * 32 + quad * 8];
                #pragma unroll
                for (int ct2 = 0; ct2 < 2; ++ct2) {
                    f32x4 c = {0.f, 0.f, 0.f, 0.f};
                    #pragma unroll
                    for (int kt2 = 0; kt2 < 2; ++kt2) c = MFMA16(Ap[kt2], Bv[ct2 * 2 + kt2], c);
                    avr[rt * 2 + ct2] = c;
                }
            }
        }
        __syncthreads();   // all waves finished reading hS(h) for QKV
        #pragma unroll
        for (int rt = 0; rt < 4; ++rt)
            #pragma unroll
            for (int ct2 = 0; ct2 < 2; ++ct2)
                #pragma unroll
                for (int i = 0; i < 4; ++i)
                    hS[(rt * 16 + quad * 4 + i) * 264 + nb + ct2 * 16 + ln]
                        = f2b(avr[rt * 2 + ct2][i]);
        __syncthreads();   // av visible to all waves

        // ---- O-proj: oacc = h + bo + av @ Wo (K=256) ----
        f32x4 oacc[8];
        #pragma unroll
        for (int rt = 0; rt < 4; ++rt)
            #pragma unroll
            for (int ct2 = 0; ct2 < 2; ++ct2) {
                float bz = bo_p[nb + ct2 * 16 + ln];
                f32x4 t = hr[rt * 2 + ct2];
                t[0] += bz; t[1] += bz; t[2] += bz; t[3] += bz;
                oacc[rt * 2 + ct2] = t;
            }
        {
            bf16x8 Bo[16];
            #pragma unroll
            for (int ct2 = 0; ct2 < 2; ++ct2)
                #pragma unroll
                for (int kt = 0; kt < 8; ++kt)
                    Bo[ct2 * 8 + kt] = *(const bf16x8*)(WoE + (size_t)(nb + ct2 * 16 + ln) * 256 + kt * 32 + quad * 8);
            #pragma unroll
            for (int rt = 0; rt < 4; ++rt) {
                bf16x8 Af[8];
                #pragma unroll
                for (int kt = 0; kt < 8; ++kt)
                    Af[kt] = *(const bf16x8*)&hS[(rt * 16 + ln) * 264 + kt * 32 + quad * 8];
                #pragma unroll
                for (int ct2 = 0; ct2 < 2; ++ct2)
                    #pragma unroll
                    for (int kt = 0; kt < 8; ++kt)
                        oacc[rt * 2 + ct2] = MFMA16(Af[kt], Bo[ct2 * 8 + kt], oacc[rt * 2 + ct2]);
            }
        }

        // ---- LN1 -> hr(oacc), hS ----
        LN(oacc, ln1g + el * 256, ln1b + el * 256);
        #pragma unroll
        for (int t = 0; t < 8; ++t) hr[t] = oacc[t];

        // ---- FF: 4 chunks of 256 FF cols; wave owns 32 FF cols per chunk ----
        f32x4 facc[8];
        {
            const float* b2_p = b2 + el * 256;
            #pragma unroll
            for (int rt = 0; rt < 4; ++rt)
                #pragma unroll
                for (int ct2 = 0; ct2 < 2; ++ct2) {
                    float bz = b2_p[nb + ct2 * 16 + ln];
                    f32x4 t = hr[rt * 2 + ct2];
                    t[0] += bz; t[1] += bz; t[2] += bz; t[3] += bz;
                    facc[rt * 2 + ct2] = t;
                }
        }
        const float* b1_p = b1 + el * 1024;
        for (int ch = 0; ch < 4; ++ch) {
            {   // W1 slice (N=32 of this 256-col chunk)
                bf16x8 B1[16];
                #pragma unroll
                for (int ct2 = 0; ct2 < 2; ++ct2)
                    #pragma unroll
                    for (int kt = 0; kt < 8; ++kt)
                        B1[ct2 * 8 + kt] = *(const bf16x8*)(W1E + (size_t)(ch * 256 + nb + ct2 * 16 + ln) * 256 + kt * 32 + quad * 8);
                float bz2[2];
                #pragma unroll
                for (int ct2 = 0; ct2 < 2; ++ct2) bz2[ct2] = b1_p[ch * 256 + nb + ct2 * 16 + ln];
                #pragma unroll
                for (int rt = 0; rt < 4; ++rt) {
                    bf16x8 Af[8];
                    #pragma unroll
                    for (int kt = 0; kt < 8; ++kt)
                        Af[kt] = *(const bf16x8*)&hS[(rt * 16 + ln) * 264 + kt * 32 + quad * 8];
                    #pragma unroll
                    for (int ct2 = 0; ct2 < 2; ++ct2) {
                        f32x4 c = {bz2[ct2], bz2[ct2], bz2[ct2], bz2[ct2]};
                        #pragma unroll
                        for (int kt = 0; kt < 8; ++kt) c = MFMA16(Af[kt], B1[ct2 * 8 + kt], c);
                        #pragma unroll
                        for (int i = 0; i < 4; ++i)
                            tS[(rt * 16 + quad * 4 + i) * 264 + nb + ct2 * 16 + ln]
                                = f2b(fmaxf(c[i], 0.f));
                    }
                }
            }
            __syncthreads();
            {   // W2 partial: K=256 (this chunk), N=32 dm cols
                bf16x8 B2[16];
                #pragma unroll
                for (int ct2 = 0; ct2 < 2; ++ct2)
                    #pragma unroll
                    for (int kt = 0; kt < 8; ++kt)
                        B2[ct2 * 8 + kt] = *(const bf16x8*)(W2E + (size_t)(nb + ct2 * 16 + ln) * 1024 + ch * 256 + kt * 32 + quad * 8);
                #pragma unroll
                for (int rt = 0; rt < 4; ++rt) {
                    bf16x8 At[8];
                    #pragma unroll
                    for (int kt = 0; kt < 8; ++kt)
                        At[kt] = *(const bf16x8*)&tS[(rt * 16 + ln) * 264 + kt * 32 + quad * 8];
                    #pragma unroll
                    for (int ct2 = 0; ct2 < 2; ++ct2)
                        #pragma unroll
                        for (int kt = 0; kt < 8; ++kt)
                            facc[rt * 2 + ct2] = MFMA16(At[kt], B2[ct2 * 8 + kt], facc[rt * 2 + ct2]);
                }
            }
            __syncthreads();
        }

        // ---- LN2 -> hr(facc), hS ----
        LN(facc, ln2g + el * 256, ln2b + el * 256);
        #pragma unroll
        for (int t = 0; t < 8; ++t) hr[t] = facc[t];
    }

    // ---- pooling + Wout + weighted combine ----
    {
        #pragma unroll
        for (int ct2 = 0; ct2 < 2; ++ct2) {
            float s_ = 0.f;
            #pragma unroll
            for (int rt = 0; rt < 4; ++rt)
                #pragma unroll
                for (int i = 0; i < 4; ++i) s_ += hr[rt * 2 + ct2][i];
            s_ += __shfl_xor(s_, 16);
            s_ += __shfl_xor(s_, 32);
            if (quad == 0) pooledS[nb + ct2 * 16 + ln] = s_ * (1.f / 64.f);
        }
        __syncthreads();
        if (tid < 64) {
            const float* Wout_p = Wout + (size_t)e * (256 * 64);
            float o = bout[e * 64 + tid];
            for (int c = 0; c < 256; ++c) o += pooledS[c] * Wout_p[c * 64 + tid];
            atomicAdd(&acc_out[b * 64 + tid], wgt * o);
        }
    }
}

// ---------------------------------------------------------------------------
__global__ __launch_bounds__(64) void final_ln_kernel(
    const float* __restrict__ acc_out, const float* __restrict__ on_g,
    const float* __restrict__ on_b, float* __restrict__ out)
{
    const int b = blockIdx.x;
    const int d = threadIdx.x;
    float v = acc_out[b * 64 + d];
    float s1 = v, s2 = v * v;
    #pragma unroll
    for (int st = 1; st < 64; st <<= 1) {
        s1 += __shfl_xor(s1, st, 64);
        s2 += __shfl_xor(s2, st, 64);
    }
    float m   = s1 * (1.f / 64.f);
    float var = s2 * (1.f / 64.f) - m * m;
    float rstd = rsqrtf(var + 1e-5f);
    out[b * 64 + d] = (v - m) * rstd * on_g[d] + on_b[d];
}

// ---------------------------------------------------------------------------
extern "C" void kernel_launch(void* const* d_in, const int* in_sizes, int n_in,
                              void* d_out, int out_size, void* d_ws, size_t ws_size,
                              hipStream_t stream)
{
    (void)in_sizes; (void)n_in; (void)out_size; (void)ws_size;
    const float* x    = (const float*)d_in[0];
    const float* Win  = (const float*)d_in[1];
    const float* bin_ = (const float*)d_in[2];
    const float* Wq   = (const float*)d_in[3];
    const float* bq   = (const float*)d_in[4];
    const float* Wk   = (const float*)d_in[5];
    const float* bk   = (const float*)d_in[6];
    const float* Wv   = (const float*)d_in[7];
    const float* bv   = (const float*)d_in[8];
    const float* Wo   = (const float*)d_in[9];
    const float* bo   = (const float*)d_in[10];
    const float* ln1g = (const float*)d_in[11];
    const float* ln1b = (const float*)d_in[12];
    const float* ln2g = (const float*)d_in[13];
    const float* ln2b = (const float*)d_in[14];
    const float* W1   = (const float*)d_in[15];
    const float* b1   = (const float*)d_in[16];
    const float* W2   = (const float*)d_in[17];
    const float* b2   = (const float*)d_in[18];
    const float* Wout = (const float*)d_in[19];
    const float* bout = (const float*)d_in[20];
    const float* Wg   = (const float*)d_in[21];
    const float* bg   = (const float*)d_in[22];
    const float* Wr   = (const float*)d_in[23];
    const float* br   = (const float*)d_in[24];
    const float* on_g = (const float*)d_in[25];
    const float* on_b = (const float*)d_in[26];
    float* out = (float*)d_out;

    // workspace carve-up
    char* ws = (char*)d_ws;
    float* acc_out = (float*)ws;                         // 131,072 B
    int*   cnt     = (int*)(ws + 131072);
    int*   rlist   = (int*)(ws + 131200);                // 16,384 B
    float* wlist   = (float*)(ws + 147584);              // 16,384 B
    short* WinT    = (short*)(ws + 164096);              //   524,288 B
    short* WqT     = (short*)(ws + 688384);              // 2,097,152 B
    short* WkT     = (short*)(ws + 2785536);
    short* WvT     = (short*)(ws + 4882688);
    short* WoT     = (short*)(ws + 6979840);
    short* W1T     = (short*)(ws + 9076992);             // 8,388,608 B
    short* W2T     = (short*)(ws + 17465600);            // 8,388,608 B

    prep_kernel<<<50176, 256, 0, stream>>>(Win, Wq, Wk, Wv, Wo, W1, W2,
        WinT, WqT, WkT, WvT, WoT, W1T, W2T, cnt);
    gate_kernel<<<512, 256, 0, stream>>>(x, Wg, bg, cnt, rlist, wlist);
    resproj_kernel<<<64, 256, 0, stream>>>(x, Wr, br, acc_out);
    expert_kernel<<<4096, 512, 0, stream>>>(x,
        WinT, bin_, WqT, bq, WkT, bk, WvT, bv, WoT, bo,
        ln1g, ln1b, ln2g, ln2b, W1T, b1, W2T, b2, Wout, bout,
        cnt, rlist, wlist, acc_out);
    final_ln_kernel<<<512, 64, 0, stream>>>(acc_out, on_g, on_b, out);
}